// Round 12
// baseline (95.718 us; speedup 1.0000x reference)
//
#include <hip/hip_runtime.h>

// Problem constants (match reference)
constexpr int B = 128;
constexpr int N = 16384;
constexpr int H = 512;
constexpr int W = 512;
constexpr int HW = H * W;                        // 262144
constexpr long long TOT = (long long)B * HW;     // 33554432 pixels
constexpr int TOT4 = (int)(TOT / 4);             // 8388608 float4

constexpr int TROWS = 8;                         // rows per tile (16 KB LDS)
constexpr int NTILES = H / TROWS;                // 64 tiles per frame
constexpr int NBUCKETS = B * NTILES;             // 8192
constexpr int CAP = 512;                         // slots/bucket (mean ~277, 14 sigma)
constexpr int NGROUPS = B * N / 4;               // 524288 groups of 4 points
constexpr int BIN_BLOCKS = NGROUPS / 512;        // 1024
constexpr int TPB = 4;                           // tiles per k_pts block
constexpr int PTS_BLOCKS = NBUCKETS / TPB;       // 2048 -> 8 blocks/CU

// ---------------------------------------------------------------------------
// Kernel 0: zero the 8192 bucket counters
// ---------------------------------------------------------------------------
__global__ void __launch_bounds__(512) k_zero(unsigned int* __restrict__ cnt) {
    cnt[blockIdx.x * 512 + threadIdx.x] = 0u;
}

// ---------------------------------------------------------------------------
// Kernel 1: bin points by (frame, 8-row tile) via LDS slot aggregation
// + fused full-BW Sum(tgt^2) stream (keeps targets LLC-hot for k_pts).
// ---------------------------------------------------------------------------
__global__ void __launch_bounds__(512) k_bin(const float4* __restrict__ pts,
                                             float4* __restrict__ buckets,
                                             unsigned int* __restrict__ cnt,
                                             const float4* __restrict__ tgt4,
                                             double* __restrict__ pbin) {
    __shared__ unsigned int lcnt[NTILES];
    __shared__ unsigned int lbase[NTILES];
    __shared__ double sacc[8];

    int tid = blockIdx.x * 512 + threadIdx.x;    // one group of 4 points
    int frame = tid >> 12;                       // 4096 groups per frame
    int fb = frame * NTILES;

    if (threadIdx.x < NTILES) lcnt[threadIdx.x] = 0;
    __syncthreads();

    float4 a = pts[tid * 3 + 0];   // x0 y0 i0 x1
    float4 b = pts[tid * 3 + 1];   // y1 i1 x2 y2
    float4 c = pts[tid * 3 + 2];   // i2 x3 y3 i3

    float xs[4] = {a.x, a.w, b.z, c.y};
    float ys[4] = {a.y, b.x, b.w, c.z};
    float is[4] = {a.z, b.y, c.x, c.w};

    int tb0[4], sl0[4], tb1[4], sl1[4];
#pragma unroll
    for (int k = 0; k < 4; ++k) {
        float x = fminf(fmaxf(xs[k], 0.0f), (float)(W - 1));
        float y = fminf(fmaxf(ys[k], 0.0f), (float)(H - 1));
        xs[k] = x; ys[k] = y;
        int y0 = (int)floorf(y);
        int y1 = min(y0 + 1, H - 1);
        int t0 = y0 >> 3;                         // TROWS = 8
        int t1 = y1 >> 3;
        tb0[k] = t0;
        sl0[k] = (int)atomicAdd(&lcnt[t0], 1u);
        if (t1 != t0) {
            tb1[k] = t1;
            sl1[k] = (int)atomicAdd(&lcnt[t1], 1u);
        } else {
            tb1[k] = -1; sl1[k] = 0;
        }
    }
    __syncthreads();

    if (threadIdx.x < NTILES)
        lbase[threadIdx.x] = atomicAdd(&cnt[fb + threadIdx.x], lcnt[threadIdx.x]);
    __syncthreads();

#pragma unroll
    for (int k = 0; k < 4; ++k) {
        float4 rec = make_float4(xs[k], ys[k], is[k], 0.0f);
        unsigned s0 = lbase[tb0[k]] + (unsigned)sl0[k];
        if (s0 < (unsigned)CAP)
            buckets[(size_t)(fb + tb0[k]) * CAP + s0] = rec;
        if (tb1[k] >= 0) {
            unsigned s1 = lbase[tb1[k]] + (unsigned)sl1[k];
            if (s1 < (unsigned)CAP)
                buckets[(size_t)(fb + tb1[k]) * CAP + s1] = rec;
        }
    }

    // ---- Sum(tgt^2): full-BW stream, 16 float4 per thread ----
    double acc = 0.0;
    for (int i = tid; i < TOT4; i += NGROUPS) {
        float4 t = tgt4[i];
        acc += (double)(t.x * t.x + t.y * t.y) + (double)(t.z * t.z + t.w * t.w);
    }
    for (int off = 32; off > 0; off >>= 1)
        acc += __shfl_down(acc, off, 64);
    int lane = threadIdx.x & 63;
    int wave = threadIdx.x >> 6;
    if (lane == 0) sacc[wave] = acc;
    __syncthreads();
    if (threadIdx.x == 0) {
        double s = 0.0;
#pragma unroll
        for (int wv = 0; wv < 8; ++wv) s += sacc[wv];
        pbin[blockIdx.x] = s;
    }
}

// ---------------------------------------------------------------------------
// Kernel 2: per-point online accumulation. Per contribution:
//   o = ds_add_rtn(tile[pix], w);  facc += w*(w + 2*o) - 2*w*tgt[pix]
// (sum over a pixel's contributions telescopes to v^2 - 2*v*t exactly).
// Tile re-zeroed by rewriting the same corners -> no per-pixel passes at all.
// ---------------------------------------------------------------------------
__global__ void __launch_bounds__(256) k_pts(const float4* __restrict__ buckets,
                                             const unsigned int* __restrict__ cnt,
                                             const float* __restrict__ tgt,
                                             double* __restrict__ ppts) {
    __shared__ float tile[TROWS * W];            // 16384 B
    __shared__ int ncache[TPB];
    __shared__ double sacc[4];

    int tid = threadIdx.x;
    int base = blockIdx.x * TPB;                 // 4 tiles, all in one frame
    int frame = base >> 6;                       // NTILES = 64
    const float* tf = tgt + (size_t)frame * HW;

    if (tid < TPB) ncache[tid] = (int)min(cnt[base + tid], (unsigned)CAP);

    // zero tile ONCE per block (returns to zero after each tile's re-zero pass)
    float4* t4 = (float4*)tile;
    float4 z = make_float4(0.f, 0.f, 0.f, 0.f);
#pragma unroll
    for (int k = 0; k < TROWS * W / 4 / 256; ++k)
        t4[tid + k * 256] = z;
    __syncthreads();

    double acc = 0.0;
#pragma unroll
    for (int j = 0; j < TPB; ++j) {
        int bid = base + j;
        int r0 = (bid & (NTILES - 1)) * TROWS;
        int n = ncache[j];
        const float4* bp = buckets + (size_t)bid * CAP;

        // at most 2 slots per thread (CAP = 512, 256 threads)
        bool v0 = tid < n, v1 = tid + 256 < n;
        float4 p0 = v0 ? bp[tid]       : make_float4(0.f, 0.f, 0.f, 0.f);
        float4 p1 = v1 ? bp[tid + 256] : make_float4(0.f, 0.f, 0.f, 0.f);

        float facc = 0.0f;
#pragma unroll
        for (int s = 0; s < 2; ++s) {
            bool valid = s == 0 ? v0 : v1;
            if (!valid) continue;
            float4 p = s == 0 ? p0 : p1;
            float x = p.x, y = p.y, inten = p.z; // clamped at bin time
            float x0f = floorf(x), y0f = floorf(y);
            float fx = x - x0f, fy = y - y0f;
            int x0 = (int)x0f, y0 = (int)y0f;
            int x1 = min(x0 + 1, W - 1);
            int y1 = min(y0 + 1, H - 1);
            int ra = y0 - r0, rb = y1 - r0;
            float w00 = inten * (1.0f - fx) * (1.0f - fy);
            float w01 = inten * fx * (1.0f - fy);
            float w10 = inten * (1.0f - fx) * fy;
            float w11 = inten * fx * fy;
            if ((unsigned)ra < (unsigned)TROWS) {
                float t00 = tf[y0 * W + x0];
                float t01 = tf[y0 * W + x1];
                float o0 = atomicAdd(&tile[ra * W + x0], w00);
                float o1 = atomicAdd(&tile[ra * W + x1], w01);
                facc += w00 * (w00 + 2.0f * o0) - 2.0f * w00 * t00;
                facc += w01 * (w01 + 2.0f * o1) - 2.0f * w01 * t01;
            }
            if ((unsigned)rb < (unsigned)TROWS) {
                float t10 = tf[y1 * W + x0];
                float t11 = tf[y1 * W + x1];
                float o2 = atomicAdd(&tile[rb * W + x0], w10);
                float o3 = atomicAdd(&tile[rb * W + x1], w11);
                facc += w10 * (w10 + 2.0f * o2) - 2.0f * w10 * t10;
                facc += w11 * (w11 + 2.0f * o3) - 2.0f * w11 * t11;
            }
        }
        acc += (double)facc;
        __syncthreads();                         // all adds for tile j done

        // ---- re-zero exactly the corners we touched (plain stores) ----
#pragma unroll
        for (int s = 0; s < 2; ++s) {
            bool valid = s == 0 ? v0 : v1;
            if (!valid) continue;
            float4 p = s == 0 ? p0 : p1;
            float x = p.x, y = p.y;
            int x0 = (int)floorf(x), y0 = (int)floorf(y);
            int x1 = min(x0 + 1, W - 1);
            int y1 = min(y0 + 1, H - 1);
            int ra = y0 - r0, rb = y1 - r0;
            if ((unsigned)ra < (unsigned)TROWS) {
                tile[ra * W + x0] = 0.0f;
                tile[ra * W + x1] = 0.0f;
            }
            if ((unsigned)rb < (unsigned)TROWS) {
                tile[rb * W + x0] = 0.0f;
                tile[rb * W + x1] = 0.0f;
            }
        }
        __syncthreads();                         // zeros visible before tile j+1
    }

    // ---- block reduction ----
    for (int off = 32; off > 0; off >>= 1)
        acc += __shfl_down(acc, off, 64);
    int lane = tid & 63;
    int wave = tid >> 6;
    if (lane == 0) sacc[wave] = acc;
    __syncthreads();
    if (tid == 0)
        ppts[blockIdx.x] = sacc[0] + sacc[1] + sacc[2] + sacc[3];
}

// ---------------------------------------------------------------------------
// Kernel 3: final combine: (Sum tgt^2 + Sum[v^2 - 2vt]) / TOT
// ---------------------------------------------------------------------------
__global__ void __launch_bounds__(512) k_final(const double* __restrict__ pbin,
                                               const double* __restrict__ ppts,
                                               float* __restrict__ out) {
    double acc = 0.0;
    for (int i = threadIdx.x; i < BIN_BLOCKS; i += 512)
        acc += pbin[i];
    for (int i = threadIdx.x; i < PTS_BLOCKS; i += 512)
        acc += ppts[i];
    for (int off = 32; off > 0; off >>= 1)
        acc += __shfl_down(acc, off, 64);
    __shared__ double sacc[8];
    int lane = threadIdx.x & 63;
    int wave = threadIdx.x >> 6;
    if (lane == 0) sacc[wave] = acc;
    __syncthreads();
    if (threadIdx.x == 0) {
        double s = 0.0;
#pragma unroll
        for (int wv = 0; wv < 8; ++wv) s += sacc[wv];
        out[0] = (float)(s / (double)TOT);
    }
}

// ---------------------------------------------------------------------------
extern "C" void kernel_launch(void* const* d_in, const int* in_sizes, int n_in,
                              void* d_out, int out_size, void* d_ws, size_t ws_size,
                              hipStream_t stream) {
    const float* pts = (const float*)d_in[0];     // [B, N, 3]
    const float* tgt = (const float*)d_in[1];     // [B, H, W]
    float* out = (float*)d_out;

    // ws layout: [cnt 32KB | pbin 8KB | ppts 16KB | pad to 64KB | buckets 64MiB]
    unsigned int* cnt = (unsigned int*)d_ws;
    double* pbin = (double*)((char*)d_ws + 32768);
    double* ppts = (double*)((char*)d_ws + 40960);
    float4* buckets = (float4*)((char*)d_ws + 65536);

    k_zero<<<NBUCKETS / 512, 512, 0, stream>>>(cnt);
    k_bin<<<BIN_BLOCKS, 512, 0, stream>>>((const float4*)pts, buckets, cnt,
                                          (const float4*)tgt, pbin);
    k_pts<<<PTS_BLOCKS, 256, 0, stream>>>(buckets, cnt, tgt, ppts);
    k_final<<<1, 512, 0, stream>>>(pbin, ppts, out);
}

// Round 13
// 87.052 us; speedup vs baseline: 1.0996x; 1.0996x over previous
//
#include <hip/hip_runtime.h>

// Problem constants (match reference)
constexpr int B = 128;
constexpr int N = 16384;
constexpr int H = 512;
constexpr int W = 512;
constexpr int HW = H * W;                        // 262144
constexpr long long TOT = (long long)B * HW;     // 33554432 pixels

constexpr int TROWS = 8;                         // rows per tile (16 KB LDS)
constexpr int NTILES = H / TROWS;                // 64 tiles per frame
constexpr int NBUCKETS = B * NTILES;             // 8192
constexpr int CAP = 512;                         // slots/bucket (mean ~277, 14 sigma)
constexpr int NGROUPS = B * N / 4;               // 524288 groups of 4 points
constexpr int BIN_BLOCKS = NGROUPS / 512;        // 1024
constexpr int TPB = 4;                           // tiles per k_pts block
constexpr int PTS_BLOCKS = NBUCKETS / TPB;       // 2048 -> 8 blocks/CU

// ---------------------------------------------------------------------------
// Kernel 0: zero the 8192 bucket counters
// ---------------------------------------------------------------------------
__global__ void __launch_bounds__(512) k_zero(unsigned int* __restrict__ cnt) {
    cnt[blockIdx.x * 512 + threadIdx.x] = 0u;
}

// ---------------------------------------------------------------------------
// Kernel 1: bin points by (frame, 8-row tile) via LDS slot aggregation.
// (UNFUSED r4/r5 form — measured ~6us. No target stream here.)
// ---------------------------------------------------------------------------
__global__ void __launch_bounds__(512) k_bin(const float4* __restrict__ pts,
                                             float4* __restrict__ buckets,
                                             unsigned int* __restrict__ cnt) {
    __shared__ unsigned int lcnt[NTILES];
    __shared__ unsigned int lbase[NTILES];

    int tid = blockIdx.x * 512 + threadIdx.x;    // one group of 4 points
    int frame = tid >> 12;                       // 4096 groups per frame
    int fb = frame * NTILES;

    if (threadIdx.x < NTILES) lcnt[threadIdx.x] = 0;
    __syncthreads();

    float4 a = pts[tid * 3 + 0];   // x0 y0 i0 x1
    float4 b = pts[tid * 3 + 1];   // y1 i1 x2 y2
    float4 c = pts[tid * 3 + 2];   // i2 x3 y3 i3

    float xs[4] = {a.x, a.w, b.z, c.y};
    float ys[4] = {a.y, b.x, b.w, c.z};
    float is[4] = {a.z, b.y, c.x, c.w};

    int tb0[4], sl0[4], tb1[4], sl1[4];
#pragma unroll
    for (int k = 0; k < 4; ++k) {
        float x = fminf(fmaxf(xs[k], 0.0f), (float)(W - 1));
        float y = fminf(fmaxf(ys[k], 0.0f), (float)(H - 1));
        xs[k] = x; ys[k] = y;
        int y0 = (int)floorf(y);
        int y1 = min(y0 + 1, H - 1);
        int t0 = y0 >> 3;                         // TROWS = 8
        int t1 = y1 >> 3;
        tb0[k] = t0;
        sl0[k] = (int)atomicAdd(&lcnt[t0], 1u);
        if (t1 != t0) {
            tb1[k] = t1;
            sl1[k] = (int)atomicAdd(&lcnt[t1], 1u);
        } else {
            tb1[k] = -1; sl1[k] = 0;
        }
    }
    __syncthreads();

    if (threadIdx.x < NTILES)
        lbase[threadIdx.x] = atomicAdd(&cnt[fb + threadIdx.x], lcnt[threadIdx.x]);
    __syncthreads();

#pragma unroll
    for (int k = 0; k < 4; ++k) {
        float4 rec = make_float4(xs[k], ys[k], is[k], 0.0f);
        unsigned s0 = lbase[tb0[k]] + (unsigned)sl0[k];
        if (s0 < (unsigned)CAP)
            buckets[(size_t)(fb + tb0[k]) * CAP + s0] = rec;
        if (tb1[k] >= 0) {
            unsigned s1 = lbase[tb1[k]] + (unsigned)sl1[k];
            if (s1 < (unsigned)CAP)
                buckets[(size_t)(fb + tb1[k]) * CAP + s1] = rec;
        }
    }
}

// ---------------------------------------------------------------------------
// Kernel 2: per-point online accumulation + fused per-tile target stream.
// Per tile j: stream its 16KB of targets (4 independent float4/thread,
// independent f32 partials -> Sum(tgt^2), warms L2 for the gathers), then
// per contribution: o = ds_add_rtn(tile[pix], w);
//                   facc += w*(w + 2*o) - 2*w*tgt[pix]
// (telescopes to v^2 - 2*v*t). Corners re-zeroed by plain stores.
// ---------------------------------------------------------------------------
__global__ void __launch_bounds__(256) k_pts(const float4* __restrict__ buckets,
                                             const unsigned int* __restrict__ cnt,
                                             const float* __restrict__ tgt,
                                             double* __restrict__ ppts) {
    __shared__ float tile[TROWS * W];            // 16384 B
    __shared__ int ncache[TPB];
    __shared__ double sacc[4];

    int tid = threadIdx.x;
    int base = blockIdx.x * TPB;                 // 4 consecutive tiles, one frame
    int frame = base >> 6;                       // NTILES = 64
    const float* tf = tgt + (size_t)frame * HW;

    if (tid < TPB) ncache[tid] = (int)min(cnt[base + tid], (unsigned)CAP);

    // zero tile ONCE per block (returns to zero after each tile's re-zero pass)
    float4* t4 = (float4*)tile;
    float4 z = make_float4(0.f, 0.f, 0.f, 0.f);
#pragma unroll
    for (int k = 0; k < TROWS * W / 4 / 256; ++k)
        t4[tid + k * 256] = z;
    __syncthreads();

    double acc = 0.0;
#pragma unroll
    for (int j = 0; j < TPB; ++j) {
        int bid = base + j;
        int r0 = (bid & (NTILES - 1)) * TROWS;
        int n = ncache[j];
        const float4* bp = buckets + (size_t)bid * CAP;

        // ---- issue this tile's target stream (1024 float4, 4/thread) ----
        const float4* tg4 = (const float4*)(tf + (size_t)r0 * W);
        float4 ta = tg4[tid];
        float4 tb = tg4[tid + 256];
        float4 tc = tg4[tid + 512];
        float4 td = tg4[tid + 768];

        // ---- bucket slots: at most 2 per thread ----
        bool v0 = tid < n, v1 = tid + 256 < n;
        float4 p0 = v0 ? bp[tid]       : make_float4(0.f, 0.f, 0.f, 0.f);
        float4 p1 = v1 ? bp[tid + 256] : make_float4(0.f, 0.f, 0.f, 0.f);

        // ---- Sum(tgt^2): 4 independent partial chains ----
        float q0 = ta.x * ta.x + ta.y * ta.y + ta.z * ta.z + ta.w * ta.w;
        float q1 = tb.x * tb.x + tb.y * tb.y + tb.z * tb.z + tb.w * tb.w;
        float q2 = tc.x * tc.x + tc.y * tc.y + tc.z * tc.z + tc.w * tc.w;
        float q3 = td.x * td.x + td.y * td.y + td.z * td.z + td.w * td.w;

        float facc = 0.0f;
#pragma unroll
        for (int s = 0; s < 2; ++s) {
            bool valid = s == 0 ? v0 : v1;
            if (!valid) continue;
            float4 p = s == 0 ? p0 : p1;
            float x = p.x, y = p.y, inten = p.z; // clamped at bin time
            float x0f = floorf(x), y0f = floorf(y);
            float fx = x - x0f, fy = y - y0f;
            int x0 = (int)x0f, y0 = (int)y0f;
            int x1 = min(x0 + 1, W - 1);
            int y1 = min(y0 + 1, H - 1);
            int ra = y0 - r0, rb = y1 - r0;
            float w00 = inten * (1.0f - fx) * (1.0f - fy);
            float w01 = inten * fx * (1.0f - fy);
            float w10 = inten * (1.0f - fx) * fy;
            float w11 = inten * fx * fy;
            if ((unsigned)ra < (unsigned)TROWS) {
                float t00 = tf[y0 * W + x0];
                float t01 = tf[y0 * W + x1];
                float o0 = atomicAdd(&tile[ra * W + x0], w00);
                float o1 = atomicAdd(&tile[ra * W + x1], w01);
                facc += w00 * (w00 + 2.0f * o0) - 2.0f * w00 * t00;
                facc += w01 * (w01 + 2.0f * o1) - 2.0f * w01 * t01;
            }
            if ((unsigned)rb < (unsigned)TROWS) {
                float t10 = tf[y1 * W + x0];
                float t11 = tf[y1 * W + x1];
                float o2 = atomicAdd(&tile[rb * W + x0], w10);
                float o3 = atomicAdd(&tile[rb * W + x1], w11);
                facc += w10 * (w10 + 2.0f * o2) - 2.0f * w10 * t10;
                facc += w11 * (w11 + 2.0f * o3) - 2.0f * w11 * t11;
            }
        }
        acc += (double)facc + (double)(q0 + q1) + (double)(q2 + q3);
        __syncthreads();                         // all adds for tile j done

        // ---- re-zero exactly the corners we touched (plain stores) ----
#pragma unroll
        for (int s = 0; s < 2; ++s) {
            bool valid = s == 0 ? v0 : v1;
            if (!valid) continue;
            float4 p = s == 0 ? p0 : p1;
            float x = p.x, y = p.y;
            int x0 = (int)floorf(x), y0 = (int)floorf(y);
            int x1 = min(x0 + 1, W - 1);
            int y1 = min(y0 + 1, H - 1);
            int ra = y0 - r0, rb = y1 - r0;
            if ((unsigned)ra < (unsigned)TROWS) {
                tile[ra * W + x0] = 0.0f;
                tile[ra * W + x1] = 0.0f;
            }
            if ((unsigned)rb < (unsigned)TROWS) {
                tile[rb * W + x0] = 0.0f;
                tile[rb * W + x1] = 0.0f;
            }
        }
        __syncthreads();                         // zeros visible before tile j+1
    }

    // ---- block reduction ----
    for (int off = 32; off > 0; off >>= 1)
        acc += __shfl_down(acc, off, 64);
    int lane = tid & 63;
    int wave = tid >> 6;
    if (lane == 0) sacc[wave] = acc;
    __syncthreads();
    if (tid == 0)
        ppts[blockIdx.x] = sacc[0] + sacc[1] + sacc[2] + sacc[3];
}

// ---------------------------------------------------------------------------
// Kernel 3: final combine: Sum[tgt^2 + v^2 - 2vt] / TOT
// ---------------------------------------------------------------------------
__global__ void __launch_bounds__(512) k_final(const double* __restrict__ ppts,
                                               float* __restrict__ out) {
    double acc = 0.0;
    for (int i = threadIdx.x; i < PTS_BLOCKS; i += 512)
        acc += ppts[i];
    for (int off = 32; off > 0; off >>= 1)
        acc += __shfl_down(acc, off, 64);
    __shared__ double sacc[8];
    int lane = threadIdx.x & 63;
    int wave = threadIdx.x >> 6;
    if (lane == 0) sacc[wave] = acc;
    __syncthreads();
    if (threadIdx.x == 0) {
        double s = 0.0;
#pragma unroll
        for (int wv = 0; wv < 8; ++wv) s += sacc[wv];
        out[0] = (float)(s / (double)TOT);
    }
}

// ---------------------------------------------------------------------------
extern "C" void kernel_launch(void* const* d_in, const int* in_sizes, int n_in,
                              void* d_out, int out_size, void* d_ws, size_t ws_size,
                              hipStream_t stream) {
    const float* pts = (const float*)d_in[0];     // [B, N, 3]
    const float* tgt = (const float*)d_in[1];     // [B, H, W]
    float* out = (float*)d_out;

    // ws layout: [cnt 32KB | ppts 16KB | pad to 64KB | buckets 64MiB]
    unsigned int* cnt = (unsigned int*)d_ws;
    double* ppts = (double*)((char*)d_ws + 32768);
    float4* buckets = (float4*)((char*)d_ws + 65536);

    k_zero<<<NBUCKETS / 512, 512, 0, stream>>>(cnt);
    k_bin<<<BIN_BLOCKS, 512, 0, stream>>>((const float4*)pts, buckets, cnt);
    k_pts<<<PTS_BLOCKS, 256, 0, stream>>>(buckets, cnt, tgt, ppts);
    k_final<<<1, 512, 0, stream>>>(ppts, out);
}